// Round 1
// 3272.618 us; speedup vs baseline: 2.0468x; 2.0468x over previous
//
#include <hip/hip_runtime.h>
#include <stdint.h>

#define B_ 8
#define T_ 256
#define V_ 32000
#define E_ 768
#define N_ 1024
#define M_ (B_*T_)      // 2048 rows, m = b*T + t
#define LDK 40          // padded LDS row stride (ushorts): 80 B = 5*16 -> aligned b128, 2-way banks

#define GW 8            // WGs per batch group (one group per batch row)
#define CW 128          // columns owned per WG (GW*CW == N_)

typedef __attribute__((ext_vector_type(8))) short short8;
typedef __attribute__((ext_vector_type(4))) float floatx4;

__device__ __forceinline__ unsigned short f2b(float x) {
  union { float f; unsigned u; } v; v.f = x;
  unsigned r = v.u + 0x7fffu + ((v.u >> 16) & 1u);  // RNE
  return (unsigned short)(r >> 16);
}

// ---------- gather embedding rows -> bf16 (M x E) ----------
__global__ __launch_bounds__(256) void k_gather(const int* __restrict__ ids,
                                                const float* __restrict__ emb,
                                                unsigned short* __restrict__ xg) {
  int m = blockIdx.x;
  long tok = ids[m];
  const float* src = emb + tok * (long)E_;
  unsigned short* dst = xg + (long)m * E_;
  for (int e = threadIdx.x; e < E_; e += 256) dst[e] = f2b(src[e]);
}

// ---------- transpose fp32 (R x C) -> bf16 (C x R) ----------
__global__ __launch_bounds__(256) void k_transpose(const float* __restrict__ src,
                                                   unsigned short* __restrict__ dst,
                                                   int R, int C) {
  __shared__ float t[32][33];
  int tx = threadIdx.x & 31, ty = threadIdx.x >> 5;  // 32x8
  int c0 = blockIdx.x * 32, r0 = blockIdx.y * 32;
  #pragma unroll
  for (int i = 0; i < 32; i += 8)
    t[ty + i][tx] = src[(long)(r0 + ty + i) * C + c0 + tx];
  __syncthreads();
  #pragma unroll
  for (int i = 0; i < 32; i += 8)
    dst[(long)(c0 + ty + i) * R + r0 + tx] = f2b(t[tx][ty + i]);
}

// ---------- bf16 MFMA GEMM: C[MxN] = A[MxK] * BT[NxK]^T ----------
// 128x128 tile, 256 thr = 4 waves in 2x2, each wave 4x4 frags of 16x16x32.
// EPI: 0 = f32 out + bias[col]; 1 = bf16 out; 2 = f32 out
template<int EPI>
__global__ __launch_bounds__(256) void k_gemm_bt(const unsigned short* __restrict__ A,
                                                 const unsigned short* __restrict__ BT,
                                                 void* __restrict__ Cout,
                                                 const float* __restrict__ bias,
                                                 int M, int N, int K) {
  __shared__ unsigned short lsA[128 * LDK];
  __shared__ unsigned short lsB[128 * LDK];
  const int tid = threadIdx.x;
  const long m0 = (long)blockIdx.y * 128;
  const long n0 = (long)blockIdx.x * 128;
  const int w = tid >> 6, l = tid & 63;
  const int wm = (w >> 1) * 64, wn = (w & 1) * 64;
  const int lm = l & 15, kq = l >> 4;
  floatx4 acc[4][4] = {};
  for (int k0 = 0; k0 < K; k0 += 32) {
    #pragma unroll
    for (int i = 0; i < 2; ++i) {   // stage 128x32 of A and BT (dims divide exactly)
      int flat = i * 256 + tid;
      int r = flat >> 2, q4 = flat & 3;
      *(uint4*)(&lsA[r * LDK + q4 * 8]) = *(const uint4*)(&A[(m0 + r) * K + k0 + q4 * 8]);
      *(uint4*)(&lsB[r * LDK + q4 * 8]) = *(const uint4*)(&BT[(n0 + r) * K + k0 + q4 * 8]);
    }
    __syncthreads();
    short8 af[4], bf[4];
    #pragma unroll
    for (int mf = 0; mf < 4; ++mf) af[mf] = *(const short8*)(&lsA[(wm + mf * 16 + lm) * LDK + kq * 8]);
    #pragma unroll
    for (int nf = 0; nf < 4; ++nf) bf[nf] = *(const short8*)(&lsB[(wn + nf * 16 + lm) * LDK + kq * 8]);
    #pragma unroll
    for (int mf = 0; mf < 4; ++mf)
      #pragma unroll
      for (int nf = 0; nf < 4; ++nf)
        acc[mf][nf] = __builtin_amdgcn_mfma_f32_16x16x32_bf16(af[mf], bf[nf], acc[mf][nf], 0, 0, 0);
    __syncthreads();
  }
  // C/D layout (m89-verified): col = lane&15, row = (lane>>4)*4 + reg
  #pragma unroll
  for (int mf = 0; mf < 4; ++mf)
    #pragma unroll
    for (int nf = 0; nf < 4; ++nf)
      #pragma unroll
      for (int r = 0; r < 4; ++r) {
        long row = m0 + wm + mf * 16 + kq * 4 + r;
        long col = n0 + wn + nf * 16 + lm;
        float v = acc[mf][nf][r];
        if (EPI == 0)      ((float*)Cout)[row * N + col] = v + bias[col];
        else if (EPI == 1) ((unsigned short*)Cout)[row * N + col] = f2b(v);
        else               ((float*)Cout)[row * N + col] = v;
      }
}

// ---------- persistent recurrence v2: batch-split flag-based pipeline ----------
// 8 independent groups (one per batch row b). Group = 8 WGs x 512 thr; WG (b,j) owns
// cols [j*128, j*128+128) with its w_bb slice resident in registers (128 VGPR B-frags/lane).
// Sync: NO fences, NO central barrier. State slices move as relaxed agent-scope atomic
// stores/loads (sc1 -> LLC, always coherent); one RELEASE atomic flag per WG per step
// (monotonic counter). Wave w consumes K in [w*128,(w+1)*128) == exactly WG w's slice,
// so each wave waits on ONE flag. Ping-pong u buffers; flag>=s+1 observed by all waves
// before the step-s __syncthreads proves every peer finished reading u[s-1], making the
// overwrite of parity (s+1)&1 safe.
__global__ __launch_bounds__(512, 2) void k_recurrence(const float* __restrict__ xbuf,
                                                       const float* __restrict__ w_bb,
                                                       const float* __restrict__ b_bb,
                                                       unsigned* __restrict__ ubuf,   // [2][8][512] dwords (2x bf16 each)
                                                       unsigned* __restrict__ flg,    // [8][16] (padded to 64B/group)
                                                       float* __restrict__ sAll) {
  const int wid = blockIdx.x;
  const int b = wid & 7;         // batch group
  const int j = wid >> 3;        // column-slice index within group
  const int tid = threadIdx.x;
  const int w = tid >> 6;        // wave 0..7: covers K in [w*128, w*128+128)
  const int l = tid & 63;
  const int lm = l & 15, kq = l >> 4;
  const int cbase = j * CW;

  __shared__ float red[2][GW][CW];   // per-parity per-wave partial sums

  // ---- one-time: load w_bb slice as MFMA B-frags (bf16), 32 x short8 = 128 VGPRs
  short8 bfrag[8][4];
  #pragma unroll
  for (int nf = 0; nf < 8; ++nf)
    #pragma unroll
    for (int kk = 0; kk < 4; ++kk) {
      const int kb = w * 128 + kk * 32 + kq * 8;
      const int c = cbase + nf * 16 + lm;
      short8 f;
      #pragma unroll
      for (int q = 0; q < 8; ++q) f[q] = (short)f2b(w_bb[(long)(kb + q) * N_ + c]);
      bfrag[nf][kk] = f;
    }

  // ---- init: publish u[0] = bf16(state0 + x_{t=0}) = bf16(x_0) for our slice
  if (w == 0) {
    float2 x0 = *(const float2*)(&xbuf[((long)b * T_) * N_ + cbase + 2 * l]);
    unsigned d = (unsigned)f2b(x0.x) | ((unsigned)f2b(x0.y) << 16);
    __hip_atomic_store(&ubuf[(0 * 8 + b) * 512 + j * 64 + l], d,
                       __ATOMIC_RELAXED, __HIP_MEMORY_SCOPE_AGENT);
    if (l == 0)
      __hip_atomic_store(&flg[b * 16 + j], 1u, __ATOMIC_RELEASE, __HIP_MEMORY_SCOPE_AGENT);
  }

  for (int s = 0; s < 4 * T_; ++s) {
    // ---- wait for producer of our K-slice: flag >= s+1 means u[s] slice published
    while (__hip_atomic_load(&flg[b * 16 + w], __ATOMIC_RELAXED, __HIP_MEMORY_SCOPE_AGENT) < (unsigned)(s + 1))
      __builtin_amdgcn_s_sleep(1);
    __asm__ __volatile__("" ::: "memory");  // keep data loads below the poll

    // ---- A-frags: 16 dwords of state slice w, fresh from LLC (sc1 loads)
    unsigned* usrc = &ubuf[((s & 1) * 8 + b) * 512 + w * 64];
    unsigned ad[4][4];
    #pragma unroll
    for (int kk = 0; kk < 4; ++kk)
      #pragma unroll
      for (int i = 0; i < 4; ++i)
        ad[kk][i] = __hip_atomic_load(&usrc[kk * 16 + kq * 4 + i],
                                      __ATOMIC_RELAXED, __HIP_MEMORY_SCOPE_AGENT);

    // ---- MFMA: A rows broadcast (all 16 rows = state) so every lane holds valid D
    floatx4 acc[8] = {};
    #pragma unroll
    for (int kk = 0; kk < 4; ++kk) {
      union { unsigned u[4]; short8 s8; } a;
      a.u[0] = ad[kk][0]; a.u[1] = ad[kk][1]; a.u[2] = ad[kk][2]; a.u[3] = ad[kk][3];
      #pragma unroll
      for (int nf = 0; nf < 8; ++nf)
        acc[nf] = __builtin_amdgcn_mfma_f32_16x16x32_bf16(a.s8, bfrag[nf][kk], acc[nf], 0, 0, 0);
    }

    // ---- per-wave partials -> LDS (compile-time acc indices; lanes kq==0 write)
    if (kq == 0) {
      #pragma unroll
      for (int nf = 0; nf < 8; ++nf)
        red[s & 1][w][nf * 16 + lm] = acc[nf][0];
    }
    __syncthreads();

    // ---- wave 0: reduce 8 waves, bias+tanh, pulse-inject, publish slice + flag
    if (w == 0) {
      const int c0 = 2 * l;
      float2 bb = *(const float2*)(&b_bb[cbase + c0]);
      float s0 = bb.x, s1 = bb.y;
      #pragma unroll
      for (int ww = 0; ww < GW; ++ww) {
        s0 += red[s & 1][ww][c0];
        s1 += red[s & 1][ww][c0 + 1];
      }
      float v0 = tanhf(s0), v1 = tanhf(s1);
      const int t = s >> 2;
      if ((s & 3) == 3) {
        float2 sv; sv.x = v0; sv.y = v1;
        *(float2*)(&sAll[((long)b * T_ + t) * N_ + cbase + c0]) = sv;  // fp32 state for LN
        if (t + 1 < T_) {
          float2 xv = *(const float2*)(&xbuf[((long)b * T_ + t + 1) * N_ + cbase + c0]);
          v0 += xv.x; v1 += xv.y;                                       // pulse inject
        }
      }
      unsigned d = (unsigned)f2b(v0) | ((unsigned)f2b(v1) << 16);
      __hip_atomic_store(&ubuf[(((s + 1) & 1) * 8 + b) * 512 + j * 64 + l], d,
                         __ATOMIC_RELAXED, __HIP_MEMORY_SCOPE_AGENT);
      if (l == 0)   // RELEASE: vmcnt-drain of the wave's data stores, then flag to LLC
        __hip_atomic_store(&flg[b * 16 + j], (unsigned)(s + 2),
                           __ATOMIC_RELEASE, __HIP_MEMORY_SCOPE_AGENT);
    }
  }
}

// ---------- row layernorm (fp32 in, bf16 out) ----------
__global__ __launch_bounds__(256) void k_layernorm(const float* __restrict__ sAll,
                                                   const float* __restrict__ gamma,
                                                   const float* __restrict__ beta,
                                                   unsigned short* __restrict__ hln) {
  long m = blockIdx.x;
  const float* x = sAll + m * N_;
  float v[4], lsum = 0.f, lsq = 0.f;
  #pragma unroll
  for (int i = 0; i < 4; ++i) {
    v[i] = x[threadIdx.x + i * 256];
    lsum += v[i]; lsq += v[i] * v[i];
  }
  #pragma unroll
  for (int off = 32; off > 0; off >>= 1) {
    lsum += __shfl_down(lsum, off);
    lsq  += __shfl_down(lsq, off);
  }
  __shared__ float sa[4], sb[4];
  int w = threadIdx.x >> 6, l = threadIdx.x & 63;
  if (l == 0) { sa[w] = lsum; sb[w] = lsq; }
  __syncthreads();
  float tsum = sa[0] + sa[1] + sa[2] + sa[3];
  float tsq  = sb[0] + sb[1] + sb[2] + sb[3];
  float mean = tsum * (1.f / N_);
  float var  = tsq * (1.f / N_) - mean * mean;   // population var (ddof=0), matches jnp.var
  float rst  = rsqrtf(var + 1e-5f);
  #pragma unroll
  for (int i = 0; i < 4; ++i) {
    int n = threadIdx.x + i * 256;
    hln[m * N_ + n] = f2b((v[i] - mean) * rst * gamma[n] + beta[n]);
  }
}

extern "C" void kernel_launch(void* const* d_in, const int* in_sizes, int n_in,
                              void* d_out, int out_size, void* d_ws, size_t ws_size,
                              hipStream_t stream) {
  const int*   ids    = (const int*)d_in[0];
  const float* emb    = (const float*)d_in[1];
  const float* w_in   = (const float*)d_in[2];
  const float* b_in   = (const float*)d_in[3];
  const float* w_bb   = (const float*)d_in[4];
  const float* b_bb   = (const float*)d_in[5];
  const float* gamma  = (const float*)d_in[6];
  const float* beta   = (const float*)d_in[7];
  const float* w_out  = (const float*)d_in[8];
  const float* w_head = (const float*)d_in[9];
  float* out = (float*)d_out;

  char* p = (char*)d_ws;
  size_t off = 0;
  auto alloc = [&](size_t bytes) { void* r = p + off; off += (bytes + 255) & ~(size_t)255; return r; };
  unsigned*       flg     = (unsigned*)alloc(512);                         // [8][16] step flags
  unsigned*       ubuf    = (unsigned*)alloc(2 * 8 * 512 * 4);             // state ping-pong, dword-packed bf16
  unsigned short* xg      = (unsigned short*)alloc((size_t)M_ * E_ * 2);   // gathered emb, bf16
  unsigned short* w_inT   = (unsigned short*)alloc((size_t)N_ * E_ * 2);   // [N][E]
  unsigned short* w_outT  = (unsigned short*)alloc((size_t)E_ * N_ * 2);   // [E][N]
  unsigned short* w_headT = (unsigned short*)alloc((size_t)V_ * E_ * 2);   // [V][E]
  float*          xbuf    = (float*)alloc((size_t)M_ * N_ * 4);            // x = emb@w_in + b_in
  float*          sAll    = (float*)alloc((size_t)M_ * N_ * 4);            // final state per (b,t)
  unsigned short* hln     = (unsigned short*)alloc((size_t)M_ * N_ * 2);   // LN(s) bf16
  unsigned short* hw      = (unsigned short*)alloc((size_t)M_ * E_ * 2);   // h @ w_out bf16

  hipMemsetAsync(flg, 0, 512, stream);                                     // flags = 0 each run
  k_gather<<<M_, 256, 0, stream>>>(ids, emb, xg);
  k_transpose<<<dim3(N_ / 32, E_ / 32), 256, 0, stream>>>(w_in, w_inT, E_, N_);
  k_transpose<<<dim3(E_ / 32, N_ / 32), 256, 0, stream>>>(w_out, w_outT, N_, E_);
  k_transpose<<<dim3(V_ / 32, E_ / 32), 256, 0, stream>>>(w_head, w_headT, E_, V_);
  k_gemm_bt<0><<<dim3(N_ / 128, M_ / 128), 256, 0, stream>>>(xg, w_inT, xbuf, b_in, M_, N_, E_);
  k_recurrence<<<B_ * GW, 512, 0, stream>>>(xbuf, w_bb, b_bb, ubuf, flg, sAll);
  k_layernorm<<<M_, 256, 0, stream>>>(sAll, gamma, beta, hln);
  k_gemm_bt<1><<<dim3(E_ / 128, M_ / 128), 256, 0, stream>>>(hln, w_outT, hw, nullptr, M_, E_, N_);
  k_gemm_bt<2><<<dim3(V_ / 128, M_ / 128), 256, 0, stream>>>(hw, w_headT, out, nullptr, M_, V_, E_);
}

// Round 2
// 3236.507 us; speedup vs baseline: 2.0696x; 1.0112x over previous
//
#include <hip/hip_runtime.h>
#include <stdint.h>

#define B_ 8
#define T_ 256
#define V_ 32000
#define E_ 768
#define N_ 1024
#define M_ (B_*T_)      // 2048 rows, m = b*T + t
#define LDK 40          // padded LDS row stride (ushorts): 80 B = 5*16 -> aligned b128, 2-way banks

#define GW 8            // WGs per batch group (one group per batch row)
#define CW 128          // columns owned per WG (GW*CW == N_)

typedef __attribute__((ext_vector_type(8))) short short8;
typedef __attribute__((ext_vector_type(4))) float floatx4;

__device__ __forceinline__ unsigned short f2b(float x) {
  union { float f; unsigned u; } v; v.f = x;
  unsigned r = v.u + 0x7fffu + ((v.u >> 16) & 1u);  // RNE
  return (unsigned short)(r >> 16);
}

// slot permutation: dword d of a 64-dword slice -> slot so that consumer kq-group's
// 16 payloads are contiguous (128 B). d = kk*16 + kq*4 + i  ->  slot = kq*16 + kk*4 + i
__device__ __forceinline__ int slot_of(int d) {
  return ((d >> 2) & 3) * 16 + (d >> 4) * 4 + (d & 3);
}

// ---------- gather embedding rows -> bf16 (M x E) ----------
__global__ __launch_bounds__(256) void k_gather(const int* __restrict__ ids,
                                                const float* __restrict__ emb,
                                                unsigned short* __restrict__ xg) {
  int m = blockIdx.x;
  long tok = ids[m];
  const float* src = emb + tok * (long)E_;
  unsigned short* dst = xg + (long)m * E_;
  for (int e = threadIdx.x; e < E_; e += 256) dst[e] = f2b(src[e]);
}

// ---------- transpose fp32 (R x C) -> bf16 (C x R) ----------
__global__ __launch_bounds__(256) void k_transpose(const float* __restrict__ src,
                                                   unsigned short* __restrict__ dst,
                                                   int R, int C) {
  __shared__ float t[32][33];
  int tx = threadIdx.x & 31, ty = threadIdx.x >> 5;  // 32x8
  int c0 = blockIdx.x * 32, r0 = blockIdx.y * 32;
  #pragma unroll
  for (int i = 0; i < 32; i += 8)
    t[ty + i][tx] = src[(long)(r0 + ty + i) * C + c0 + tx];
  __syncthreads();
  #pragma unroll
  for (int i = 0; i < 32; i += 8)
    dst[(long)(c0 + ty + i) * R + r0 + tx] = f2b(t[tx][ty + i]);
}

// ---------- bf16 MFMA GEMM: C[MxN] = A[MxK] * BT[NxK]^T ----------
// 128x128 tile, 256 thr = 4 waves in 2x2, each wave 4x4 frags of 16x16x32.
// EPI: 0 = f32 out + bias[col]; 1 = bf16 out; 2 = f32 out
template<int EPI>
__global__ __launch_bounds__(256) void k_gemm_bt(const unsigned short* __restrict__ A,
                                                 const unsigned short* __restrict__ BT,
                                                 void* __restrict__ Cout,
                                                 const float* __restrict__ bias,
                                                 int M, int N, int K) {
  __shared__ unsigned short lsA[128 * LDK];
  __shared__ unsigned short lsB[128 * LDK];
  const int tid = threadIdx.x;
  const long m0 = (long)blockIdx.y * 128;
  const long n0 = (long)blockIdx.x * 128;
  const int w = tid >> 6, l = tid & 63;
  const int wm = (w >> 1) * 64, wn = (w & 1) * 64;
  const int lm = l & 15, kq = l >> 4;
  floatx4 acc[4][4] = {};
  for (int k0 = 0; k0 < K; k0 += 32) {
    #pragma unroll
    for (int i = 0; i < 2; ++i) {   // stage 128x32 of A and BT (dims divide exactly)
      int flat = i * 256 + tid;
      int r = flat >> 2, q4 = flat & 3;
      *(uint4*)(&lsA[r * LDK + q4 * 8]) = *(const uint4*)(&A[(m0 + r) * K + k0 + q4 * 8]);
      *(uint4*)(&lsB[r * LDK + q4 * 8]) = *(const uint4*)(&BT[(n0 + r) * K + k0 + q4 * 8]);
    }
    __syncthreads();
    short8 af[4], bf[4];
    #pragma unroll
    for (int mf = 0; mf < 4; ++mf) af[mf] = *(const short8*)(&lsA[(wm + mf * 16 + lm) * LDK + kq * 8]);
    #pragma unroll
    for (int nf = 0; nf < 4; ++nf) bf[nf] = *(const short8*)(&lsB[(wn + nf * 16 + lm) * LDK + kq * 8]);
    #pragma unroll
    for (int mf = 0; mf < 4; ++mf)
      #pragma unroll
      for (int nf = 0; nf < 4; ++nf)
        acc[mf][nf] = __builtin_amdgcn_mfma_f32_16x16x32_bf16(af[mf], bf[nf], acc[mf][nf], 0, 0, 0);
    __syncthreads();
  }
  // C/D layout (m89-verified): col = lane&15, row = (lane>>4)*4 + reg
  #pragma unroll
  for (int mf = 0; mf < 4; ++mf)
    #pragma unroll
    for (int nf = 0; nf < 4; ++nf)
      #pragma unroll
      for (int r = 0; r < 4; ++r) {
        long row = m0 + wm + mf * 16 + kq * 4 + r;
        long col = n0 + wn + nf * 16 + lm;
        float v = acc[mf][nf][r];
        if (EPI == 0)      ((float*)Cout)[row * N + col] = v + bias[col];
        else if (EPI == 1) ((unsigned short*)Cout)[row * N + col] = f2b(v);
        else               ((float*)Cout)[row * N + col] = v;
      }
}

// ---------- persistent recurrence v3: self-validating payload pipeline ----------
// 8 independent groups (one per batch row b); group = 8 WGs x 512 thr; WG (b,j) owns
// cols [j*128,(j+1)*128) with w_bb slice in registers. Each producer lane publishes ONE
// relaxed agent-scope u64 atomic: {lo: 2 bf16 state cols, hi: step tag}. Data+tag are in
// the same 8B store -> no release, no vmcnt drain, no separate flag. Consumer wave w
// polls its 16 contiguous u64s of slice w; when all 16 tags reach s+1 the data is
// already in registers. Backpressure: producer j overwrites a tag-s slot only at end of
// its iteration s, by which time it has observed tag s+1 from all 8 producers, i.e.
// every WG passed its iter-(s-1) syncthreads and therefore finished reading tag-s data.
// Tags are monotonic per launch; pbuf is memset to 0 before each launch.
__global__ __launch_bounds__(512, 2) void k_recurrence(const float* __restrict__ xbuf,
                                                       const float* __restrict__ w_bb,
                                                       const float* __restrict__ b_bb,
                                                       unsigned long long* __restrict__ pbuf, // [2][8][8][64] u64
                                                       float* __restrict__ sAll) {
  const int wid = blockIdx.x;
  const int b = wid & 7;         // batch group
  const int j = wid >> 3;        // column-slice index within group
  const int tid = threadIdx.x;
  const int w = tid >> 6;        // wave 0..7: consumes K in [w*128, w*128+128) == slice w
  const int l = tid & 63;
  const int lm = l & 15, kq = l >> 4;
  const int cbase = j * CW;

  __shared__ float red[2][GW][CW];   // per-parity per-wave partial sums

  // ---- one-time: load w_bb slice as MFMA B-frags (bf16), 32 x short8 = 128 regs
  short8 bfrag[8][4];
  #pragma unroll
  for (int nf = 0; nf < 8; ++nf)
    #pragma unroll
    for (int kk = 0; kk < 4; ++kk) {
      const int kb = w * 128 + kk * 32 + kq * 8;
      const int c = cbase + nf * 16 + lm;
      short8 f;
      #pragma unroll
      for (int q = 0; q < 8; ++q) f[q] = (short)f2b(w_bb[(long)(kb + q) * N_ + c]);
      bfrag[nf][kk] = f;
    }

  // ---- init: publish u[0] = bf16(x_0) for our slice, tag 1, parity 0
  if (w == 0) {
    float2 x0 = *(const float2*)(&xbuf[((long)b * T_) * N_ + cbase + 2 * l]);
    unsigned d = (unsigned)f2b(x0.x) | ((unsigned)f2b(x0.y) << 16);
    __hip_atomic_store(&pbuf[((0 * 8 + b) * 8 + j) * 64 + slot_of(l)],
                       ((unsigned long long)1u << 32) | d,
                       __ATOMIC_RELAXED, __HIP_MEMORY_SCOPE_AGENT);
  }

  for (int s = 0; s < 4 * T_; ++s) {
    // ---- poll own K-slice: 16 contiguous u64 payloads; tag>=s+1 validates the data
    const unsigned long long* src = &pbuf[(((s & 1) * 8 + b) * 8 + w) * 64 + kq * 16];
    const unsigned tgt = (unsigned)(s + 1);
    unsigned long long pay[16];
    for (;;) {
      #pragma unroll
      for (int q = 0; q < 16; ++q)
        pay[q] = __hip_atomic_load(&src[q], __ATOMIC_RELAXED, __HIP_MEMORY_SCOPE_AGENT);
      unsigned mn = 0xffffffffu;
      #pragma unroll
      for (int q = 0; q < 16; ++q) {
        unsigned tg = (unsigned)(pay[q] >> 32);
        mn = mn < tg ? mn : tg;
      }
      if (mn >= tgt) break;
    }

    // ---- MFMA: A rows broadcast (all 16 rows = state) so every lane holds valid D
    floatx4 acc[8] = {};
    #pragma unroll
    for (int kk = 0; kk < 4; ++kk) {
      union { unsigned u[4]; short8 s8; } a;
      #pragma unroll
      for (int i = 0; i < 4; ++i) a.u[i] = (unsigned)pay[kk * 4 + i];
      #pragma unroll
      for (int nf = 0; nf < 8; ++nf)
        acc[nf] = __builtin_amdgcn_mfma_f32_16x16x32_bf16(a.s8, bfrag[nf][kk], acc[nf], 0, 0, 0);
    }

    // ---- per-wave partials -> LDS (lanes kq==0 carry cols; all D rows identical)
    if (kq == 0) {
      #pragma unroll
      for (int nf = 0; nf < 8; ++nf)
        red[s & 1][w][nf * 16 + lm] = acc[nf][0];
    }
    __syncthreads();

    // ---- wave 0: reduce 8 waves, bias+tanh, pulse-inject, publish payloads
    if (w == 0) {
      const int c0 = 2 * l;
      float2 bb = *(const float2*)(&b_bb[cbase + c0]);
      float s0 = bb.x, s1 = bb.y;
      #pragma unroll
      for (int ww = 0; ww < GW; ++ww) {
        s0 += red[s & 1][ww][c0];
        s1 += red[s & 1][ww][c0 + 1];
      }
      float v0 = tanhf(s0), v1 = tanhf(s1);
      const int t = s >> 2;
      if ((s & 3) == 3) {
        float2 sv; sv.x = v0; sv.y = v1;
        *(float2*)(&sAll[((long)b * T_ + t) * N_ + cbase + c0]) = sv;  // fp32 state for LN
        if (t + 1 < T_) {
          float2 xv = *(const float2*)(&xbuf[((long)b * T_ + t + 1) * N_ + cbase + c0]);
          v0 += xv.x; v1 += xv.y;                                       // pulse inject
        }
      }
      unsigned d = (unsigned)f2b(v0) | ((unsigned)f2b(v1) << 16);
      __hip_atomic_store(&pbuf[((((s + 1) & 1) * 8 + b) * 8 + j) * 64 + slot_of(l)],
                         ((unsigned long long)(unsigned)(s + 2) << 32) | d,
                         __ATOMIC_RELAXED, __HIP_MEMORY_SCOPE_AGENT);
    }
  }
}

// ---------- row layernorm (fp32 in, bf16 out) ----------
__global__ __launch_bounds__(256) void k_layernorm(const float* __restrict__ sAll,
                                                   const float* __restrict__ gamma,
                                                   const float* __restrict__ beta,
                                                   unsigned short* __restrict__ hln) {
  long m = blockIdx.x;
  const float* x = sAll + m * N_;
  float v[4], lsum = 0.f, lsq = 0.f;
  #pragma unroll
  for (int i = 0; i < 4; ++i) {
    v[i] = x[threadIdx.x + i * 256];
    lsum += v[i]; lsq += v[i] * v[i];
  }
  #pragma unroll
  for (int off = 32; off > 0; off >>= 1) {
    lsum += __shfl_down(lsum, off);
    lsq  += __shfl_down(lsq, off);
  }
  __shared__ float sa[4], sb[4];
  int w = threadIdx.x >> 6, l = threadIdx.x & 63;
  if (l == 0) { sa[w] = lsum; sb[w] = lsq; }
  __syncthreads();
  float tsum = sa[0] + sa[1] + sa[2] + sa[3];
  float tsq  = sb[0] + sb[1] + sb[2] + sb[3];
  float mean = tsum * (1.f / N_);
  float var  = tsq * (1.f / N_) - mean * mean;   // population var (ddof=0), matches jnp.var
  float rst  = rsqrtf(var + 1e-5f);
  #pragma unroll
  for (int i = 0; i < 4; ++i) {
    int n = threadIdx.x + i * 256;
    hln[m * N_ + n] = f2b((v[i] - mean) * rst * gamma[n] + beta[n]);
  }
}

extern "C" void kernel_launch(void* const* d_in, const int* in_sizes, int n_in,
                              void* d_out, int out_size, void* d_ws, size_t ws_size,
                              hipStream_t stream) {
  const int*   ids    = (const int*)d_in[0];
  const float* emb    = (const float*)d_in[1];
  const float* w_in   = (const float*)d_in[2];
  const float* b_in   = (const float*)d_in[3];
  const float* w_bb   = (const float*)d_in[4];
  const float* b_bb   = (const float*)d_in[5];
  const float* gamma  = (const float*)d_in[6];
  const float* beta   = (const float*)d_in[7];
  const float* w_out  = (const float*)d_in[8];
  const float* w_head = (const float*)d_in[9];
  float* out = (float*)d_out;

  char* p = (char*)d_ws;
  size_t off = 0;
  auto alloc = [&](size_t bytes) { void* r = p + off; off += (bytes + 255) & ~(size_t)255; return r; };
  unsigned long long* pbuf = (unsigned long long*)alloc(2 * 8 * 8 * 64 * 8); // tagged state payloads
  unsigned short* xg      = (unsigned short*)alloc((size_t)M_ * E_ * 2);   // gathered emb, bf16
  unsigned short* w_inT   = (unsigned short*)alloc((size_t)N_ * E_ * 2);   // [N][E]
  unsigned short* w_outT  = (unsigned short*)alloc((size_t)E_ * N_ * 2);   // [E][N]
  unsigned short* w_headT = (unsigned short*)alloc((size_t)V_ * E_ * 2);   // [V][E]
  float*          xbuf    = (float*)alloc((size_t)M_ * N_ * 4);            // x = emb@w_in + b_in
  float*          sAll    = (float*)alloc((size_t)M_ * N_ * 4);            // final state per (b,t)
  unsigned short* hln     = (unsigned short*)alloc((size_t)M_ * N_ * 2);   // LN(s) bf16
  unsigned short* hw      = (unsigned short*)alloc((size_t)M_ * E_ * 2);   // h @ w_out bf16

  hipMemsetAsync(pbuf, 0, 2 * 8 * 8 * 64 * 8, stream);                     // clear tags each launch
  k_gather<<<M_, 256, 0, stream>>>(ids, emb, xg);
  k_transpose<<<dim3(N_ / 32, E_ / 32), 256, 0, stream>>>(w_in, w_inT, E_, N_);
  k_transpose<<<dim3(E_ / 32, N_ / 32), 256, 0, stream>>>(w_out, w_outT, N_, E_);
  k_transpose<<<dim3(V_ / 32, E_ / 32), 256, 0, stream>>>(w_head, w_headT, E_, V_);
  k_gemm_bt<0><<<dim3(N_ / 128, M_ / 128), 256, 0, stream>>>(xg, w_inT, xbuf, b_in, M_, N_, E_);
  k_recurrence<<<B_ * GW, 512, 0, stream>>>(xbuf, w_bb, b_bb, pbuf, sAll);
  k_layernorm<<<M_, 256, 0, stream>>>(sAll, gamma, beta, hln);
  k_gemm_bt<1><<<dim3(E_ / 128, M_ / 128), 256, 0, stream>>>(hln, w_outT, hw, nullptr, M_, E_, N_);
  k_gemm_bt<2><<<dim3(V_ / 128, M_ / 128), 256, 0, stream>>>(hw, w_headT, out, nullptr, M_, V_, E_);
}